// Round 2
// baseline (113.359 us; speedup 1.0000x reference)
//
#include <hip/hip_runtime.h>

// Problem: out[b] = sum_{m<64} prod_{l<256} eps[samples[b,l], m, l]
// B=4096, L=256, LOCAL_DIM=2, M=64.
// Key facts: samples are 1-bit; eps values for fixed (m,l) are wave-uniform
// in a lane-per-b layout -> scalar loads; products over l stay per-lane in
// registers; sum over m is split across waves and combined with atomicAdd.
#define BQ 4096
#define LQ 256
#define MQ 64

// Kernel 1: pack samples (B,L) int32 {0,1} into transposed bitfield.
// packed64[c2*BQ + b] holds bits for l in [c2*64, c2*64+64), bit j = l%64.
// Block = 256 thr (4 waves), wave w handles b = blockIdx.x*4 + w.
__global__ __launch_bounds__(256) void qgps_pack(const int* __restrict__ samples,
                                                 unsigned long long* __restrict__ packed) {
    const int wave = threadIdx.x >> 6;
    const int lane = threadIdx.x & 63;
    const int b = blockIdx.x * 4 + wave;
    const int* row = samples + b * LQ;
#pragma unroll
    for (int c2 = 0; c2 < 4; ++c2) {
        int s = row[c2 * 64 + lane];              // coalesced 256B per wave
        unsigned long long mask = __ballot(s & 1); // bit lane = l = c2*64+lane
        if (lane == 0) packed[c2 * BQ + b] = mask;
    }
}

// Kernel 2: main. lane = b within a 64-b group; each wave covers 2 m's.
// grid = 64 bgroups * 32 mchunks / 4 waves-per-block = 512 blocks.
__global__ __launch_bounds__(256) void qgps_main(const unsigned long long* __restrict__ packed,
                                                 const float* __restrict__ eps,
                                                 float* __restrict__ out) {
    const int wave = __builtin_amdgcn_readfirstlane(threadIdx.x >> 6);
    const int lane = threadIdx.x & 63;
    const int bg = blockIdx.x >> 3;        // 0..63
    const int mq = blockIdx.x & 7;         // 8 blocks per bgroup
    const int mc = mq * 4 + wave;          // mchunk 0..31
    const int m0 = mc * 2;                 // this wave: m0, m0+1
    const int b = bg * 64 + lane;

    // Wave-uniform eps row pointers (compiler scalarizes -> s_load).
    const float* e0a = eps + m0 * LQ;                 // s=0, m0
    const float* e1a = eps + MQ * LQ + m0 * LQ;       // s=1, m0
    const float* e0b = e0a + LQ;                      // s=0, m0+1
    const float* e1b = e1a + LQ;                      // s=1, m0+1

    float pa = 1.0f, pb = 1.0f;
    for (int c2 = 0; c2 < 4; ++c2) {
        unsigned long long w = packed[c2 * BQ + b];   // coalesced 512B per wave
        unsigned int wlo = (unsigned int)w;
        unsigned int whi = (unsigned int)(w >> 32);
        const int l0 = c2 * 64;
#pragma unroll 16
        for (int j = 0; j < 32; ++j) {
            bool s = (wlo >> j) & 1;
            pa *= s ? e1a[l0 + j] : e0a[l0 + j];
            pb *= s ? e1b[l0 + j] : e0b[l0 + j];
        }
#pragma unroll 16
        for (int j = 0; j < 32; ++j) {
            bool s = (whi >> j) & 1;
            pa *= s ? e1a[l0 + 32 + j] : e0a[l0 + 32 + j];
            pb *= s ? e1b[l0 + 32 + j] : e0b[l0 + 32 + j];
        }
    }
    atomicAdd(&out[b], pa + pb);
}

extern "C" void kernel_launch(void* const* d_in, const int* in_sizes, int n_in,
                              void* d_out, int out_size, void* d_ws, size_t ws_size,
                              hipStream_t stream) {
    const int* samples = (const int*)d_in[0];              // (B, L) int32
    const float* eps = (const float*)d_in[1];              // (2, M, L) fp32
    float* out = (float*)d_out;                            // (B,) fp32
    unsigned long long* packed = (unsigned long long*)d_ws; // 128 KB scratch

    // d_out is poisoned 0xAA; atomicAdd accumulation needs zeros.
    hipMemsetAsync(out, 0, BQ * sizeof(float), stream);

    qgps_pack<<<BQ / 4, 256, 0, stream>>>(samples, packed);
    qgps_main<<<512, 256, 0, stream>>>(packed, eps, out);
}

// Round 3
// 67.982 us; speedup vs baseline: 1.6675x; 1.6675x over previous
//
#include <hip/hip_runtime.h>

// Problem: out[b] = sum_{m<64} prod_{l<256} eps[samples[b,l], m, l]
// B=4096, L=256, LOCAL_DIM=2, M=64.
//
// Reformulation (samples are 1-bit):
//   prod_l eps[s_bl, m, l] = C[m] * prod_l (1 + s_bl * rm1[m,l])
// with rm1 = eps1/eps0 - 1 and C[m] = prod_l eps0[m,l]  (eps0 ~ N(1,0.05),
// never near 0 for this fixed-seed input, so the division is safe).
// This makes all eps-derived loads UNCONDITIONAL and WAVE-UNIFORM -> s_load
// (scalar pipe), avoiding R2's divergent select-of-address vector loads.
#define BQ 4096
#define LQ 256
#define MQ 64

// ---- Kernel 1: pack samples (B,L) int32 {0,1} into transposed bitfield.
// packed[c2*BQ + b] bit j = samples[b, c2*64 + j].
__global__ __launch_bounds__(256) void qgps_pack(const int* __restrict__ samples,
                                                 unsigned long long* __restrict__ packed) {
    const int wave = threadIdx.x >> 6;
    const int lane = threadIdx.x & 63;
    const int b = blockIdx.x * 4 + wave;
    const int* row = samples + b * LQ;
#pragma unroll
    for (int c2 = 0; c2 < 4; ++c2) {
        int s = row[c2 * 64 + lane];               // coalesced 256B per wave
        unsigned long long mask = __ballot(s & 1); // bit lane = l = c2*64+lane
        if (lane == 0) packed[c2 * BQ + b] = mask;
    }
}

// ---- Kernel 2: per-m precompute. One wave per m.
// rm1[m][l] = eps1[m][l]/eps0[m][l] - 1 ;  C[m] = prod_l eps0[m][l]
__global__ __launch_bounds__(64) void qgps_prep(const float* __restrict__ eps,
                                                float* __restrict__ rm1,
                                                float* __restrict__ C) {
    const int m = blockIdx.x;
    const int lane = threadIdx.x;
    const float* e0 = eps + m * LQ;
    const float* e1 = eps + (MQ + m) * LQ;
    float q = 1.0f;
#pragma unroll
    for (int k = 0; k < 4; ++k) {
        int l = lane * 4 + k;
        float a = e0[l];
        q *= a;
        rm1[m * LQ + l] = e1[l] / a - 1.0f;
    }
#pragma unroll
    for (int off = 32; off > 0; off >>= 1)
        q *= __shfl_xor(q, off, 64);
    if (lane == 0) C[m] = q;
}

// ---- Kernel 3: main. lane = b within a 64-b group; one m per wave.
// grid = 64 bgroups * 16 mblocks = 1024 blocks; 4096 waves = 16/CU.
__global__ __launch_bounds__(256) void qgps_main(const unsigned long long* __restrict__ packed,
                                                 const float* __restrict__ rm1,
                                                 const float* __restrict__ C,
                                                 float* __restrict__ out) {
    __shared__ float red[4][64];
    const int wave = __builtin_amdgcn_readfirstlane(threadIdx.x >> 6);
    const int lane = threadIdx.x & 63;
    const int bg = blockIdx.x >> 4;       // 0..63
    const int mb = blockIdx.x & 15;       // 0..15
    const int m  = mb * 4 + wave;         // wave-uniform m
    const int b  = bg * 64 + lane;

    const float* __restrict__ rrow = rm1 + m * LQ;  // wave-uniform pointer

    float p0 = 1.0f, p1 = 1.0f;           // 2 chains for ILP
    for (int c2 = 0; c2 < 4; ++c2) {
        unsigned long long w = packed[c2 * BQ + b]; // coalesced 512B per wave
        unsigned int wlo = (unsigned int)w, whi = (unsigned int)(w >> 32);
        const float* r0 = rrow + c2 * 64;
#pragma unroll
        for (int j = 0; j < 32; j += 2) {
            float f0 = (float)((wlo >> j) & 1u);
            float f1 = (float)((wlo >> (j + 1)) & 1u);
            p0 *= 1.0f + f0 * r0[j];       // v_fma: 1.0 inline, rm1 in SGPR
            p1 *= 1.0f + f1 * r0[j + 1];
        }
        const float* r1 = r0 + 32;
#pragma unroll
        for (int j = 0; j < 32; j += 2) {
            float f0 = (float)((whi >> j) & 1u);
            float f1 = (float)((whi >> (j + 1)) & 1u);
            p0 *= 1.0f + f0 * r1[j];
            p1 *= 1.0f + f1 * r1[j + 1];
        }
    }
    red[wave][lane] = C[m] * (p0 * p1);
    __syncthreads();
    if (wave == 0) {
        float s = (red[0][lane] + red[1][lane]) + (red[2][lane] + red[3][lane]);
        atomicAdd(&out[b], s);            // 16 atomics per out[b]
    }
}

extern "C" void kernel_launch(void* const* d_in, const int* in_sizes, int n_in,
                              void* d_out, int out_size, void* d_ws, size_t ws_size,
                              hipStream_t stream) {
    const int* samples = (const int*)d_in[0];   // (B, L) int32
    const float* eps = (const float*)d_in[1];   // (2, M, L) fp32
    float* out = (float*)d_out;                 // (B,) fp32

    // ws layout: packed bits | rm1 | C
    unsigned long long* packed = (unsigned long long*)d_ws;          // 128 KB
    float* rm1 = (float*)((char*)d_ws + 4 * BQ * sizeof(unsigned long long)); // 64 KB
    float* C   = rm1 + MQ * LQ;                                      // 256 B

    // d_out is poisoned 0xAA; atomicAdd accumulation needs zeros.
    hipMemsetAsync(out, 0, BQ * sizeof(float), stream);

    qgps_pack<<<BQ / 4, 256, 0, stream>>>(samples, packed);
    qgps_prep<<<MQ, 64, 0, stream>>>(eps, rm1, C);
    qgps_main<<<1024, 256, 0, stream>>>(packed, rm1, C, out);
}

// Round 4
// 64.355 us; speedup vs baseline: 1.7615x; 1.0563x over previous
//
#include <hip/hip_runtime.h>

// out[b] = sum_{m<64} prod_{l<256} eps[samples[b,l], m, l]
// B=4096, L=256, LOCAL_DIM=2, M=64.
//
// Reformulation (1-bit samples):
//   prod_l eps[s,m,l] = C[m] * prod_l (1 + s_bl * rm1[m,l]),
//   rm1 = eps1/eps0 - 1, C[m] = prod_l eps0[m,l].
// Inner element = 3 VALU ops, zero per-element VMEM:
//   msk = sbfe(bits,j,1)          // -bit (all-ones or 0)
//   fr  = and(r, msk)             // bit ? r : +0.0  (bitwise)
//   p   = fma(p, fr, p)           // p *= (1 + bit*r)
// rm1 rows live in LDS (staged once/block); reads are wave-uniform
// ds_read_b128 broadcasts (conflict-free, off the VMEM pipe).
#define BQ 4096
#define LQ 256
#define MQ 64

// ---- Kernel A: fused pack + prep + out-zero (one dispatch).
// blocks [0,1024): pack samples bits -> packed[c2*BQ+b]
// blocks [1024,1040): rm1/C precompute (wave per m)
// blocks [1040,1044): zero out[0..4096)
__global__ __launch_bounds__(256) void qgps_prep_all(const int* __restrict__ samples,
                                                     const float* __restrict__ eps,
                                                     unsigned long long* __restrict__ packed,
                                                     float* __restrict__ rm1,
                                                     float* __restrict__ C,
                                                     float* __restrict__ out) {
    const int blk = blockIdx.x;
    const int wave = threadIdx.x >> 6;
    const int lane = threadIdx.x & 63;
    if (blk < 1024) {
        const int b = blk * 4 + wave;
        const int* row = samples + b * LQ;
#pragma unroll
        for (int c2 = 0; c2 < 4; ++c2) {
            unsigned long long mask = __ballot(row[c2 * 64 + lane] & 1);
            if (lane == 0) packed[c2 * BQ + b] = mask;
        }
    } else if (blk < 1040) {
        const int m = (blk - 1024) * 4 + wave;
        const float* e0 = eps + m * LQ;
        const float* e1 = eps + (MQ + m) * LQ;
        float q = 1.0f;
#pragma unroll
        for (int k = 0; k < 4; ++k) {
            int l = lane * 4 + k;
            float a = e0[l];
            q *= a;
            rm1[m * LQ + l] = e1[l] / a - 1.0f;
        }
#pragma unroll
        for (int off = 32; off > 0; off >>= 1) q *= __shfl_xor(q, off, 64);
        if (lane == 0) C[m] = q;
    } else {
        // 4 blocks * 256 threads * 4 floats = 4096
        float4* o4 = (float4*)out;
        o4[(blk - 1040) * 256 + threadIdx.x] = make_float4(0.f, 0.f, 0.f, 0.f);
    }
}

__device__ __forceinline__ float bit_and_r(unsigned w, int j, float r) {
    int msk = __builtin_amdgcn_sbfe((int)w, j, 1);  // -bit: 0xFFFFFFFF or 0
    return __uint_as_float(__float_as_uint(r) & (unsigned)msk);
}

// ---- Kernel B: main. 1024 blocks; bg = blk>>4 (64 b's, lane=b),
// mb = blk&15, wave's m = mb*4+wave. rm1 rows staged in LDS.
__global__ __launch_bounds__(256) void qgps_main(const unsigned long long* __restrict__ packed,
                                                 const float* __restrict__ rm1,
                                                 const float* __restrict__ C,
                                                 float* __restrict__ out) {
    __shared__ float lr[1024];       // 4 m-rows x 256
    __shared__ float red[4][64];
    const int tid = threadIdx.x;
    const int wave = tid >> 6;
    const int lane = tid & 63;
    const int bg = blockIdx.x >> 4;
    const int mb = blockIdx.x & 15;

    // Stage this block's 4 rm1 rows (coalesced, 4 KB).
#pragma unroll
    for (int i = 0; i < 4; ++i) lr[tid + i * 256] = rm1[mb * 1024 + tid + i * 256];
    __syncthreads();

    const int b = bg * 64 + lane;
    const int m = mb * 4 + wave;
    const float4* r4 = (const float4*)&lr[wave * 256];  // wave-uniform -> broadcast

    float p0 = 1.0f, p1 = 1.0f;  // two chains to cover fma latency
#pragma unroll
    for (int c2 = 0; c2 < 4; ++c2) {
        unsigned long long w = packed[c2 * BQ + b];  // coalesced 512B/wave
        unsigned int wlo = (unsigned int)w, whi = (unsigned int)(w >> 32);
#pragma unroll
        for (int q = 0; q < 8; ++q) {                // bits 4q..4q+3 of wlo
            float4 r = r4[c2 * 16 + q];
            p0 = fmaf(p0, bit_and_r(wlo, 4 * q + 0, r.x), p0);
            p1 = fmaf(p1, bit_and_r(wlo, 4 * q + 1, r.y), p1);
            p0 = fmaf(p0, bit_and_r(wlo, 4 * q + 2, r.z), p0);
            p1 = fmaf(p1, bit_and_r(wlo, 4 * q + 3, r.w), p1);
        }
#pragma unroll
        for (int q = 0; q < 8; ++q) {                // bits of whi
            float4 r = r4[c2 * 16 + 8 + q];
            p0 = fmaf(p0, bit_and_r(whi, 4 * q + 0, r.x), p0);
            p1 = fmaf(p1, bit_and_r(whi, 4 * q + 1, r.y), p1);
            p0 = fmaf(p0, bit_and_r(whi, 4 * q + 2, r.z), p0);
            p1 = fmaf(p1, bit_and_r(whi, 4 * q + 3, r.w), p1);
        }
    }
    red[wave][lane] = C[m] * (p0 * p1);
    __syncthreads();
    if (wave == 0) {
        float s = (red[0][lane] + red[1][lane]) + (red[2][lane] + red[3][lane]);
        atomicAdd(&out[b], s);       // 16 atomics per out[b]
    }
}

extern "C" void kernel_launch(void* const* d_in, const int* in_sizes, int n_in,
                              void* d_out, int out_size, void* d_ws, size_t ws_size,
                              hipStream_t stream) {
    const int* samples = (const int*)d_in[0];   // (B, L) int32
    const float* eps = (const float*)d_in[1];   // (2, M, L) fp32
    float* out = (float*)d_out;                 // (B,) fp32

    unsigned long long* packed = (unsigned long long*)d_ws;                       // 128 KB
    float* rm1 = (float*)((char*)d_ws + 4 * BQ * sizeof(unsigned long long));     // 64 KB
    float* C = rm1 + MQ * LQ;                                                     // 256 B

    qgps_prep_all<<<1044, 256, 0, stream>>>(samples, eps, packed, rm1, C, out);
    qgps_main<<<1024, 256, 0, stream>>>(packed, rm1, C, out);
}